// Round 4
// baseline (438.311 us; speedup 1.0000x reference)
//
#include <hip/hip_runtime.h>

// out[b,s,e] = prod_{j<=e} cos(x[b,s,j])  -- cumprod of cos along last axis.
// x: f32[16, 8192, 512] -> 131072 rows of 512 floats (2 KiB each).
//
// One 64-lane wave per TWO rows. Per row: lane i owns float4 #i (first half)
// and float4 #(64+i) (second half) -- perfectly coalesced dwordx4. All 4 loads
// for both rows are issued before any dependent math (memory-level
// parallelism), and the 4 shuffle-scan chains are independent (ILP).
// Output stored with non-temporal hint (stream-once, don't allocate L2) --
// via a native clang ext_vector_type, since __builtin_nontemporal_store
// rejects HIP_vector_type<float,4>*.
// cos via __cosf (v_cos_f32): abs error ~1e-6 << 2e-2 threshold.

#define ROW_LEN 512

typedef float v4f __attribute__((ext_vector_type(4)));

__global__ __launch_bounds__(256) void cumprod_cos_kernel(
    const float* __restrict__ x, float* __restrict__ out, int nrows) {
    const int wave_in_block = threadIdx.x >> 6;
    const int lane          = threadIdx.x & 63;
    const int pair = blockIdx.x * (blockDim.x >> 6) + wave_in_block;  // 2 rows per wave
    const int row0 = pair * 2;
    if (row0 >= nrows) return;

    const size_t base0 = (size_t)row0 * ROW_LEN;
    const size_t base1 = base0 + ROW_LEN;
    const v4f* __restrict__ xin0 = reinterpret_cast<const v4f*>(x + base0);
    const v4f* __restrict__ xin1 = reinterpret_cast<const v4f*>(x + base1);
    v4f* __restrict__ op0 = reinterpret_cast<v4f*>(out + base0);
    v4f* __restrict__ op1 = reinterpret_cast<v4f*>(out + base1);

    // Issue all 4 coalesced 16B loads up-front.
    v4f a0 = xin0[lane];
    v4f b0 = xin0[64 + lane];
    v4f a1 = xin1[lane];
    v4f b1 = xin1[64 + lane];

    // Hardware cosine + lane-local inclusive prefix products (4 chunks)
    float q0 = __cosf(a0.x);
    float q1 = q0 * __cosf(a0.y);
    float q2 = q1 * __cosf(a0.z);
    float q3 = q2 * __cosf(a0.w);
    float r0 = __cosf(b0.x);
    float r1 = r0 * __cosf(b0.y);
    float r2 = r1 * __cosf(b0.z);
    float r3 = r2 * __cosf(b0.w);
    float s0 = __cosf(a1.x);
    float s1 = s0 * __cosf(a1.y);
    float s2 = s1 * __cosf(a1.z);
    float s3 = s2 * __cosf(a1.w);
    float t0 = __cosf(b1.x);
    float t1 = t0 * __cosf(b1.y);
    float t2 = t1 * __cosf(b1.z);
    float t3 = t2 * __cosf(b1.w);

    // Four independent wave-wide product scans (6 shfl_up steps each).
    float sq = q3, sr = r3, ss = s3, st = t3;
    #pragma unroll
    for (int off = 1; off < 64; off <<= 1) {
        float nq = __shfl_up(sq, off, 64);
        float nr = __shfl_up(sr, off, 64);
        float ns = __shfl_up(ss, off, 64);
        float nt = __shfl_up(st, off, 64);
        bool act = (lane >= off);
        sq *= act ? nq : 1.0f;
        sr *= act ? nr : 1.0f;
        ss *= act ? ns : 1.0f;
        st *= act ? nt : 1.0f;
    }
    float eq = __shfl_up(sq, 1, 64);
    float er = __shfl_up(sr, 1, 64);
    float es = __shfl_up(ss, 1, 64);
    float et = __shfl_up(st, 1, 64);
    if (lane == 0) { eq = 1.0f; er = 1.0f; es = 1.0f; et = 1.0f; }
    const float totq = __shfl(sq, 63, 64);   // product of row0 first half
    const float tots = __shfl(ss, 63, 64);   // product of row1 first half
    er *= totq;
    et *= tots;

    v4f o0 = { eq * q0, eq * q1, eq * q2, eq * q3 };
    v4f o1 = { er * r0, er * r1, er * r2, er * r3 };
    v4f o2 = { es * s0, es * s1, es * s2, es * s3 };
    v4f o3 = { et * t0, et * t1, et * t2, et * t3 };

    __builtin_nontemporal_store(o0, op0 + lane);
    __builtin_nontemporal_store(o1, op0 + 64 + lane);
    __builtin_nontemporal_store(o2, op1 + lane);
    __builtin_nontemporal_store(o3, op1 + 64 + lane);
}

extern "C" void kernel_launch(void* const* d_in, const int* in_sizes, int n_in,
                              void* d_out, int out_size, void* d_ws, size_t ws_size,
                              hipStream_t stream) {
    const float* x = (const float*)d_in[0];
    float* out = (float*)d_out;
    const int nrows = in_sizes[0] / ROW_LEN;            // 131072
    const int rows_per_block = 8;                        // 4 waves x 2 rows
    const int grid = (nrows + rows_per_block - 1) / rows_per_block;
    cumprod_cos_kernel<<<grid, 256, 0, stream>>>(x, out, nrows);
}